// Round 3
// baseline (922.963 us; speedup 1.0000x reference)
//
#include <hip/hip_runtime.h>
#include <hip/hip_bf16.h>

#define DFEAT 64

// ---------------- degree / norm ----------------

__global__ __launch_bounds__(256) void deg_init_k(float* __restrict__ deg, int n) {
    int i = blockIdx.x * 256 + threadIdx.x;
    if (i < n) deg[i] = 1.0f;  // self loop
}

__global__ __launch_bounds__(256) void deg_count_k(const int* __restrict__ dst,
                                                   float* __restrict__ deg, int E) {
    int e = blockIdx.x * 256 + threadIdx.x;
    if (e < E) atomicAdd(&deg[dst[e]], 1.0f);
}

__global__ __launch_bounds__(256) void dinv_k(float* __restrict__ deg, int n) {
    int i = blockIdx.x * 256 + threadIdx.x;
    if (i < n) deg[i] = rsqrtf(deg[i]);  // deg >= 1 always (self loop)
}

// ---------------- dense GEMM: A[n,64] = scale[n] * (X[n,64] @ W[64,64]) ----------------

__global__ __launch_bounds__(256) void gemm64_k(const float* __restrict__ X,
                                                const float* __restrict__ W,
                                                const float* __restrict__ scale,
                                                float* __restrict__ A, int nrows) {
    __shared__ float Ws[64 * 64];
    __shared__ float Xs[4 * 64];
    for (int i = threadIdx.x; i < 64 * 64; i += 256) Ws[i] = W[i];
    int lane = threadIdx.x & 63;
    int wv = threadIdx.x >> 6;  // 0..3

    for (int base = blockIdx.x * 4; base < nrows; base += gridDim.x * 4) {
        __syncthreads();  // covers W load on first iter, protects Xs reuse after
        {
            int rr = base + (threadIdx.x >> 6);
            Xs[threadIdx.x] = (rr < nrows) ? X[rr * 64 + (threadIdx.x & 63)] : 0.0f;
        }
        __syncthreads();
        int r = base + wv;
        if (r < nrows) {
            float acc = 0.0f;
#pragma unroll
            for (int k = 0; k < 64; ++k)
                acc += Xs[wv * 64 + k] * Ws[k * 64 + lane];
            A[r * 64 + lane] = acc * scale[r];
        }
    }
}

// ---------------- aggregation ----------------

// B = A  (self-loop term, pre-dinv[dst] scaling)
__global__ __launch_bounds__(256) void copy_k(const float* __restrict__ A,
                                              float* __restrict__ B, int total) {
    int i = blockIdx.x * 256 + threadIdx.x;
    if (i < total) B[i] = A[i];
}

// B[dst,:] += A[src,:]   (64 threads per edge; all norm factors folded elsewhere)
__global__ __launch_bounds__(256) void scatter_k(const int* __restrict__ src,
                                                 const int* __restrict__ dst,
                                                 const float* __restrict__ A,
                                                 float* __restrict__ B, int E) {
    int t = blockIdx.x * 256 + threadIdx.x;
    int e = t >> 6;
    int f = t & 63;
    if (e < E) {
        int s = src[e];
        int d = dst[e];
        atomicAdd(&B[d * 64 + f], A[s * 64 + f]);
    }
}

// B[i,:] = relu(dinv[i] * B[i,:] + b[:])
__global__ __launch_bounds__(256) void relu_epi_k(float* __restrict__ B,
                                                  const float* __restrict__ dinv,
                                                  const float* __restrict__ bias, int total) {
    int i = blockIdx.x * 256 + threadIdx.x;
    if (i < total) B[i] = fmaxf(fmaf(dinv[i >> 6], B[i], bias[i & 63]), 0.0f);
}

// out[i,:] = dinv[i] * out[i,:] + b[:] + x[i,:]
__global__ __launch_bounds__(256) void final_epi_k(float* __restrict__ B,
                                                   const float* __restrict__ dinv,
                                                   const float* __restrict__ bias,
                                                   const float* __restrict__ xres, int total) {
    int i = blockIdx.x * 256 + threadIdx.x;
    if (i < total) B[i] = fmaf(dinv[i >> 6], B[i], bias[i & 63] + xres[i]);
}

// ---------------- launch ----------------

extern "C" void kernel_launch(void* const* d_in, const int* in_sizes, int n_in,
                              void* d_out, int out_size, void* d_ws, size_t ws_size,
                              hipStream_t stream) {
    const float* x = (const float*)d_in[0];
    const int* ei = (const int*)d_in[1];   // harness passes integer inputs as int32
    const float* W1 = (const float*)d_in[2];
    const float* b1 = (const float*)d_in[3];
    const float* W2 = (const float*)d_in[4];
    const float* b2 = (const float*)d_in[5];
    float* out = (float*)d_out;

    const int N = in_sizes[0] / DFEAT;       // 100000
    const int E = in_sizes[1] / 2;           // 1600000
    const int total = N * DFEAT;             // 6.4M

    const int* src = ei;
    const int* dst = ei + E;

    // workspace layout (total ws use = N*64*4 + N*4 ~= 26 MB)
    float* A = (float*)d_ws;                                  // N*64 floats (scaled h)
    float* dinv = (float*)((char*)d_ws + (size_t)total * 4);  // N floats

    const int gN = (N + 255) / 256;
    const int gE = (E + 255) / 256;
    const int gT = (total + 255) / 256;
    const int gS = (int)(((long long)E * 64 + 255) / 256);

    // degrees -> dinv
    deg_init_k<<<gN, 256, 0, stream>>>(dinv, N);
    deg_count_k<<<gE, 256, 0, stream>>>(dst, dinv, E);
    dinv_k<<<gN, 256, 0, stream>>>(dinv, N);

    // ---- layer 1 ----  (out[] doubles as aggregation buffer / x1)
    gemm64_k<<<1024, 256, 0, stream>>>(x, W1, dinv, A, N);   // A = dinv * (x @ W1)
    copy_k<<<gT, 256, 0, stream>>>(A, out, total);           // self term
    scatter_k<<<gS, 256, 0, stream>>>(src, dst, A, out, E);  // += neighbors
    relu_epi_k<<<gT, 256, 0, stream>>>(out, dinv, b1, total);

    // ---- layer 2 ----
    gemm64_k<<<1024, 256, 0, stream>>>(out, W2, dinv, A, N); // A = dinv * (x1 @ W2)
    copy_k<<<gT, 256, 0, stream>>>(A, out, total);           // self term (overwrites x1)
    scatter_k<<<gS, 256, 0, stream>>>(src, dst, A, out, E);  // += neighbors
    final_epi_k<<<gT, 256, 0, stream>>>(out, dinv, b2, x, total);
}

// Round 4
// 484.298 us; speedup vs baseline: 1.9058x; 1.9058x over previous
//
#include <hip/hip_runtime.h>
#include <hip/hip_bf16.h>

#define DFEAT 64

// ---------------- CSR build ----------------

__global__ __launch_bounds__(256) void zero_k(int* __restrict__ cnt, int n) {
    int i = blockIdx.x * 256 + threadIdx.x;
    if (i < n) cnt[i] = 0;
}

__global__ __launch_bounds__(256) void count_k(const int* __restrict__ dst,
                                               int* __restrict__ cnt, int E) {
    int e = blockIdx.x * 256 + threadIdx.x;
    if (e < E) atomicAdd(&cnt[dst[e]], 1);
}

// per-block sums of cnt
__global__ __launch_bounds__(256) void scan1_k(const int* __restrict__ cnt,
                                               int* __restrict__ bsum, int n) {
    __shared__ int s[256];
    int i = blockIdx.x * 256 + threadIdx.x;
    s[threadIdx.x] = (i < n) ? cnt[i] : 0;
    __syncthreads();
    for (int off = 128; off > 0; off >>= 1) {
        if (threadIdx.x < off) s[threadIdx.x] += s[threadIdx.x + off];
        __syncthreads();
    }
    if (threadIdx.x == 0) bsum[blockIdx.x] = s[0];
}

// exclusive scan of block sums (single block, up to 1024 blocks' worth)
__global__ __launch_bounds__(1024) void scan2_k(int* __restrict__ bsum, int nb) {
    __shared__ int s[1024];
    int t = threadIdx.x;
    int v = (t < nb) ? bsum[t] : 0;
    s[t] = v;
    __syncthreads();
    for (int off = 1; off < 1024; off <<= 1) {
        int u = (t >= off) ? s[t - off] : 0;
        __syncthreads();
        s[t] += u;
        __syncthreads();
    }
    if (t < nb) bsum[t] = s[t] - v;  // exclusive
}

// per-block exclusive scan + base -> row_start, cursor; also dinv = rsqrt(cnt+1)
__global__ __launch_bounds__(256) void scan3_k(const int* __restrict__ cnt,
                                               const int* __restrict__ bsum,
                                               int* __restrict__ row_start,
                                               int* __restrict__ cursor,
                                               float* __restrict__ dinv, int n) {
    __shared__ int s[256];
    int i = blockIdx.x * 256 + threadIdx.x;
    int v = (i < n) ? cnt[i] : 0;
    s[threadIdx.x] = v;
    __syncthreads();
    for (int off = 1; off < 256; off <<= 1) {
        int u = (threadIdx.x >= off) ? s[threadIdx.x - off] : 0;
        __syncthreads();
        s[threadIdx.x] += u;
        __syncthreads();
    }
    int incl = s[threadIdx.x];
    if (i < n) {
        int excl = bsum[blockIdx.x] + incl - v;
        row_start[i] = excl;
        cursor[i] = excl;
        dinv[i] = rsqrtf((float)v + 1.0f);  // +1 self loop
        if (i == n - 1) row_start[n] = excl + v;
    }
}

__global__ __launch_bounds__(256) void fill_k(const int* __restrict__ src,
                                              const int* __restrict__ dst,
                                              int* __restrict__ cursor,
                                              int* __restrict__ csr_src, int E) {
    int e = blockIdx.x * 256 + threadIdx.x;
    if (e < E) {
        int pos = atomicAdd(&cursor[dst[e]], 1);
        csr_src[pos] = src[e];
    }
}

// ---------------- dense GEMM: A[n,64] = scale[n] * (X[n,64] @ W[64,64]) ----------------

__global__ __launch_bounds__(256) void gemm64_k(const float* __restrict__ X,
                                                const float* __restrict__ W,
                                                const float* __restrict__ scale,
                                                float* __restrict__ A, int nrows) {
    __shared__ float Ws[64 * 64];
    __shared__ float Xs[4 * 64];
    for (int i = threadIdx.x; i < 64 * 64; i += 256) Ws[i] = W[i];
    int lane = threadIdx.x & 63;
    int wv = threadIdx.x >> 6;  // 0..3

    for (int base = blockIdx.x * 4; base < nrows; base += gridDim.x * 4) {
        __syncthreads();
        {
            int rr = base + (threadIdx.x >> 6);
            Xs[threadIdx.x] = (rr < nrows) ? X[rr * 64 + (threadIdx.x & 63)] : 0.0f;
        }
        __syncthreads();
        int r = base + wv;
        if (r < nrows) {
            float acc = 0.0f;
#pragma unroll
            for (int k = 0; k < 64; ++k)
                acc += Xs[wv * 64 + k] * Ws[k * 64 + lane];
            A[r * 64 + lane] = acc * scale[r];
        }
    }
}

// ---------------- gather aggregation (one wave per node) ----------------
// out[i] = relu(dinv[i]*(A[i] + sum_{j->i} A[j]) + b)

__global__ __launch_bounds__(256) void gather_relu_k(const int* __restrict__ row_start,
                                                     const int* __restrict__ csr_src,
                                                     const float* __restrict__ A,
                                                     const float* __restrict__ dinv,
                                                     const float* __restrict__ bias,
                                                     float* __restrict__ out, int N) {
    int node = blockIdx.x * 4 + (threadIdx.x >> 6);
    int lane = threadIdx.x & 63;
    if (node >= N) return;
    float acc = A[(size_t)node * 64 + lane];  // self loop
    int e = row_start[node], e1 = row_start[node + 1];
    for (; e + 2 <= e1; e += 2) {
        int s0 = csr_src[e], s1 = csr_src[e + 1];
        float v0 = A[(size_t)s0 * 64 + lane];
        float v1 = A[(size_t)s1 * 64 + lane];
        acc += v0 + v1;
    }
    if (e < e1) acc += A[(size_t)csr_src[e] * 64 + lane];
    out[(size_t)node * 64 + lane] = fmaxf(fmaf(dinv[node], acc, bias[lane]), 0.0f);
}

// out[i] = dinv[i]*(A[i] + sum) + b + x[i]
__global__ __launch_bounds__(256) void gather_res_k(const int* __restrict__ row_start,
                                                    const int* __restrict__ csr_src,
                                                    const float* __restrict__ A,
                                                    const float* __restrict__ dinv,
                                                    const float* __restrict__ bias,
                                                    const float* __restrict__ xres,
                                                    float* __restrict__ out, int N) {
    int node = blockIdx.x * 4 + (threadIdx.x >> 6);
    int lane = threadIdx.x & 63;
    if (node >= N) return;
    float acc = A[(size_t)node * 64 + lane];
    int e = row_start[node], e1 = row_start[node + 1];
    for (; e + 2 <= e1; e += 2) {
        int s0 = csr_src[e], s1 = csr_src[e + 1];
        float v0 = A[(size_t)s0 * 64 + lane];
        float v1 = A[(size_t)s1 * 64 + lane];
        acc += v0 + v1;
    }
    if (e < e1) acc += A[(size_t)csr_src[e] * 64 + lane];
    size_t idx = (size_t)node * 64 + lane;
    out[idx] = fmaf(dinv[node], acc, bias[lane] + xres[idx]);
}

// ---------------- launch ----------------

extern "C" void kernel_launch(void* const* d_in, const int* in_sizes, int n_in,
                              void* d_out, int out_size, void* d_ws, size_t ws_size,
                              hipStream_t stream) {
    const float* x = (const float*)d_in[0];
    const int* ei = (const int*)d_in[1];  // int32 per harness
    const float* W1 = (const float*)d_in[2];
    const float* b1 = (const float*)d_in[3];
    const float* W2 = (const float*)d_in[4];
    const float* b2 = (const float*)d_in[5];
    float* out = (float*)d_out;

    const int N = in_sizes[0] / DFEAT;  // 100000
    const int E = in_sizes[1] / 2;      // 1600000
    const int total = N * DFEAT;

    const int* src = ei;
    const int* dst = ei + E;

    // workspace layout (~33.6 MB)
    char* w = (char*)d_ws;
    size_t o = 0;
    float* A = (float*)(w + o);        o += (size_t)total * 4;
    float* dinv = (float*)(w + o);     o += (size_t)N * 4;
    int* cnt = (int*)(w + o);          o += (size_t)N * 4;
    int* row_start = (int*)(w + o);    o += (size_t)(N + 4) * 4;
    int* cursor = (int*)(w + o);       o += (size_t)N * 4;
    int* csr_src = (int*)(w + o);      o += (size_t)E * 4;
    int* bsum = (int*)(w + o);

    const int gN = (N + 255) / 256;   // also = number of scan blocks (<=1024 assumed)
    const int gE = (E + 255) / 256;
    const int gG = (N + 3) / 4;

    // ---- CSR build (shared by both layers) ----
    zero_k<<<gN, 256, 0, stream>>>(cnt, N);
    count_k<<<gE, 256, 0, stream>>>(dst, cnt, E);
    scan1_k<<<gN, 256, 0, stream>>>(cnt, bsum, N);
    scan2_k<<<1, 1024, 0, stream>>>(bsum, gN);
    scan3_k<<<gN, 256, 0, stream>>>(cnt, bsum, row_start, cursor, dinv, N);
    fill_k<<<gE, 256, 0, stream>>>(src, dst, cursor, csr_src, E);

    // ---- layer 1 ----
    gemm64_k<<<1024, 256, 0, stream>>>(x, W1, dinv, A, N);  // A = dinv*(x@W1)
    gather_relu_k<<<gG, 256, 0, stream>>>(row_start, csr_src, A, dinv, b1, out, N);

    // ---- layer 2 ---- (x1 lives in d_out, consumed by gemm before overwrite)
    gemm64_k<<<1024, 256, 0, stream>>>(out, W2, dinv, A, N);  // A = dinv*(x1@W2)
    gather_res_k<<<gG, 256, 0, stream>>>(row_start, csr_src, A, dinv, b2, x, out, N);
}